// Round 4
// baseline (1764.180 us; speedup 1.0000x reference)
//
#include <hip/hip_runtime.h>
#include <math.h>

#define DEPTH 18
#define NNODES ((1 << DEPTH) - 1)
#define NVOCAB 50000

typedef unsigned short bf16raw;
typedef __bf16 bf16x8 __attribute__((ext_vector_type(8)));
typedef float f32x4 __attribute__((ext_vector_type(4)));
typedef short short8 __attribute__((ext_vector_type(8)));

__device__ __forceinline__ float sigm(float x) { return 1.0f / (1.0f + __expf(-x)); }

__device__ __forceinline__ float bf2f(bf16raw u) {
    union { unsigned int i; float f; } v;
    v.i = ((unsigned int)u) << 16;
    return v.f;
}
__device__ __forceinline__ bf16raw f2bf(float f) {
    union { float f; unsigned int i; } v;
    v.f = f;
    unsigned int r = v.i + 0x7FFFu + ((v.i >> 16) & 1u);  // RNE
    return (bf16raw)(r >> 16);
}

// ---------------------------------------------------------------------------
// prep: fp32 embeds -> bf16 table
// ---------------------------------------------------------------------------
__global__ __launch_bounds__(256) void k_prep_embeds(const float* __restrict__ src,
                                                     bf16raw* __restrict__ dst, int n4)
{
    int i = blockIdx.x * blockDim.x + threadIdx.x;
    if (i < n4) {
        float4 v = ((const float4*)src)[i];
        ushort4 o;
        o.x = f2bf(v.x); o.y = f2bf(v.y); o.z = f2bf(v.z); o.w = f2bf(v.w);
        ((ushort4*)dst)[i] = o;
    }
}

// ---------------------------------------------------------------------------
// prep: BcatT[col 0..639][k 0..383] bf16.  Gate order: 0=i, 1=u, 2=o, 3=f1, 4=f2
//  k 0-127   : Wx[jj][k]
//  k 128-255 : Wh[jj][*] for i,u,o,f1 ; 0 for f2
//  k 256-383 : Wh[jj][*] for i,u,o,f2 ; 0 for f1
// bias_cat[col] = bx[jj] + bh[jj]
// ---------------------------------------------------------------------------
__global__ __launch_bounds__(128) void k_prep_bcat(
    const float* __restrict__ Wix, const float* __restrict__ bix,
    const float* __restrict__ Wih, const float* __restrict__ bih,
    const float* __restrict__ Wfx, const float* __restrict__ bfx,
    const float* __restrict__ Wfh, const float* __restrict__ bfh,
    const float* __restrict__ Wox, const float* __restrict__ box_,
    const float* __restrict__ Woh, const float* __restrict__ boh,
    const float* __restrict__ Wux, const float* __restrict__ bux,
    const float* __restrict__ Wuh, const float* __restrict__ buh,
    bf16raw* __restrict__ BcatT, float* __restrict__ bias_cat)
{
    const int j = blockIdx.x;        // 0..639
    const int grp = j >> 7, jj = j & 127;
    const float *Wx, *Wh, *bx, *bh;
    switch (grp) {
        case 0: Wx = Wix; Wh = Wih; bx = bix;  bh = bih; break;
        case 1: Wx = Wux; Wh = Wuh; bx = bux;  bh = buh; break;
        case 2: Wx = Wox; Wh = Woh; bx = box_; bh = boh; break;
        default: Wx = Wfx; Wh = Wfh; bx = bfx; bh = bfh; break;
    }
    for (int k = threadIdx.x; k < 384; k += blockDim.x) {
        float v;
        if (k < 128) {
            v = Wx[jj * 128 + k];
        } else if (k < 256) {
            v = (grp == 4) ? 0.f : Wh[jj * 128 + (k - 128)];
        } else {
            v = (grp == 3) ? 0.f : Wh[jj * 128 + (k - 256)];
        }
        BcatT[(long)j * 384 + k] = f2bf(v);
    }
    if (threadIdx.x == 0) bias_cat[j] = bx[jj] + bh[jj];
}

// ---------------------------------------------------------------------------
// k_fused: per 128-node tile, loop cb over gate groups (i,u,o,f1,f2), run the
// 128x128 MFMA GEMM vs Bcat columns, combine gates in registers, write h,c
// coalesced via LDS, fused logits + log_softmax + loss.
// ---------------------------------------------------------------------------
__global__ __launch_bounds__(256, 2) void k_fused(
    const bf16raw* __restrict__ embeds_bf, const int* __restrict__ words,
    bf16raw* __restrict__ h_all, bf16raw* __restrict__ c_all,
    const bf16raw* __restrict__ BcatT, const float* __restrict__ bias_cat,
    const float* __restrict__ Wout, const float* __restrict__ bout,
    const int* __restrict__ labels,
    float* __restrict__ partials, float* __restrict__ out,
    int off, int nm, int leaf, int isroot)
{
    __shared__ __align__(16) bf16raw sA[128 * 40];
    __shared__ __align__(16) bf16raw sB[128 * 40];
    __shared__ __align__(16) bf16raw sT[128 * 136];
    __shared__ float sWout[5 * 128];
    __shared__ float sLoss;

    const int t = threadIdx.x;
    const int mbase = blockIdx.x * 128;
    const int Kc = leaf ? 128 : 384;
    const int ncb = leaf ? 3 : 5;

    for (int i = t; i < 640; i += 256) sWout[i] = Wout[i];
    if (t == 0) sLoss = 0.f;

    // staging: 2 threads per row, 16 elems (32 B) each
    const int srow = t >> 1;
    const int shalf = (t & 1) * 16;
    const long glr = (long)off + mbase + srow;
    const bf16raw* ax  = embeds_bf + (long)words[glr] * 128;
    const bf16raw* ah1 = h_all + (2 * glr + 1) * 128;
    const bf16raw* ah2 = h_all + (2 * glr + 2) * 128;

    const int lane = t & 63;
    const int w = t >> 6;
    const int wrow = (w >> 1) * 64;
    const int wcol = (w & 1) * 64;
    const int lrow = lane & 15;
    const int lquad = lane >> 4;
    const int lkoff = lquad * 8;

    float cval[4][4][4];
    unsigned int opk[4][4][2];

    for (int cb = 0; cb < ncb; ++cb) {
        const bf16raw* bsrc = BcatT + ((long)(cb * 128 + srow)) * 384;
        f32x4 acc[4][4];
#pragma unroll
        for (int i = 0; i < 4; i++)
#pragma unroll
            for (int j = 0; j < 4; j++) acc[i][j] = (f32x4){0.f, 0.f, 0.f, 0.f};

        for (int kt = 0; kt < Kc; kt += 32) {
            const bf16raw* asrc = (kt < 128) ? ax : ((kt < 256) ? ah1 : ah2);
            const int kl = kt & 127;
            short8 av0 = *(const short8*)(asrc + kl + shalf);
            short8 av1 = *(const short8*)(asrc + kl + shalf + 8);
            short8 bv0 = *(const short8*)(bsrc + kt + shalf);
            short8 bv1 = *(const short8*)(bsrc + kt + shalf + 8);
            __syncthreads();
            *(short8*)&sA[srow * 40 + shalf] = av0;
            *(short8*)&sA[srow * 40 + shalf + 8] = av1;
            *(short8*)&sB[srow * 40 + shalf] = bv0;
            *(short8*)&sB[srow * 40 + shalf + 8] = bv1;
            __syncthreads();
            bf16x8 af[4], bfr[4];
#pragma unroll
            for (int i = 0; i < 4; i++) {
                af[i]  = *(const bf16x8*)&sA[(wrow + i * 16 + lrow) * 40 + lkoff];
                bfr[i] = *(const bf16x8*)&sB[(wcol + i * 16 + lrow) * 40 + lkoff];
            }
#pragma unroll
            for (int i = 0; i < 4; i++)
#pragma unroll
                for (int j = 0; j < 4; j++)
                    acc[i][j] = __builtin_amdgcn_mfma_f32_16x16x32_bf16(af[i], bfr[j], acc[i][j], 0, 0, 0);
        }

        // gate combine (C/D layout: col = lane&15, row = quad*4 + reg)
        if (cb == 0) {          // i
#pragma unroll
            for (int i = 0; i < 4; i++)
#pragma unroll
                for (int jj = 0; jj < 4; jj++) {
                    const float bias = bias_cat[wcol + jj * 16 + lrow];
#pragma unroll
                    for (int r = 0; r < 4; r++)
                        cval[i][jj][r] = sigm(acc[i][jj][r] + bias);
                }
        } else if (cb == 1) {   // u
#pragma unroll
            for (int i = 0; i < 4; i++)
#pragma unroll
                for (int jj = 0; jj < 4; jj++) {
                    const float bias = bias_cat[128 + wcol + jj * 16 + lrow];
#pragma unroll
                    for (int r = 0; r < 4; r++)
                        cval[i][jj][r] *= tanhf(acc[i][jj][r] + bias);
                }
        } else if (cb == 2) {   // o (stash packed bf16)
#pragma unroll
            for (int i = 0; i < 4; i++)
#pragma unroll
                for (int jj = 0; jj < 4; jj++) {
                    const float bias = bias_cat[256 + wcol + jj * 16 + lrow];
#pragma unroll
                    for (int rp = 0; rp < 2; rp++) {
                        float o0 = sigm(acc[i][jj][rp * 2] + bias);
                        float o1 = sigm(acc[i][jj][rp * 2 + 1] + bias);
                        opk[i][jj][rp] = (unsigned int)f2bf(o0) |
                                         ((unsigned int)f2bf(o1) << 16);
                    }
                }
        } else {                // f1 (cb==3) / f2 (cb==4)
            const int csel = cb - 3;
#pragma unroll
            for (int i = 0; i < 4; i++)
#pragma unroll
                for (int jj = 0; jj < 4; jj++) {
                    const int j = wcol + jj * 16 + lrow;
                    const float bias = bias_cat[cb * 128 + j];
#pragma unroll
                    for (int r = 0; r < 4; r++) {
                        const int m = wrow + i * 16 + lquad * 4 + r;
                        const long g = (long)off + mbase + m;
                        bf16raw cc = c_all[(2 * g + 1 + csel) * 128 + j];
                        cval[i][jj][r] += sigm(acc[i][jj][r] + bias) * bf2f(cc);
                    }
                }
        }
    }

    // h scatter into sT
#pragma unroll
    for (int i = 0; i < 4; i++)
#pragma unroll
        for (int jj = 0; jj < 4; jj++)
#pragma unroll
            for (int r = 0; r < 4; r++) {
                const int m = wrow + i * 16 + lquad * 4 + r;
                const int j = wcol + jj * 16 + lrow;
                float o = bf2f((bf16raw)((opk[i][jj][r >> 1] >> ((r & 1) * 16)) & 0xFFFF));
                float h = o * tanhf(cval[i][jj][r]);
                sT[m * 136 + j] = f2bf(h);
            }
    __syncthreads();

    const long gbase = (long)off + mbase;
    // coalesced h write
#pragma unroll
    for (int s = 0; s < 8; ++s) {
        int ci = t + 256 * s;
        int row = ci >> 4, c8 = (ci & 15) * 8;
        if (row < nm)
            *(short8*)(h_all + (gbase + row) * 128 + c8) = *(const short8*)&sT[row * 136 + c8];
    }
    // logits + loss (2 threads per row)
    {
        const int row = t >> 1, half = t & 1;
        float p[5] = {0.f, 0.f, 0.f, 0.f, 0.f};
        for (int k = 0; k < 64; ++k) {
            float hv = bf2f(sT[row * 136 + half * 64 + k]);
#pragma unroll
            for (int l = 0; l < 5; l++) p[l] += hv * sWout[l * 128 + half * 64 + k];
        }
#pragma unroll
        for (int l = 0; l < 5; l++) p[l] += __shfl_down(p[l], 1);
        if (half == 0 && row < nm) {
            float lg[5], mx = -1e30f;
#pragma unroll
            for (int l = 0; l < 5; l++) {
                lg[l] = p[l] + bout[l];
                mx = fmaxf(mx, lg[l]);
            }
            float se = 0.f;
#pragma unroll
            for (int l = 0; l < 5; l++) se += __expf(lg[l] - mx);
            float lse = __logf(se) + mx;
            int lab = labels[gbase + row];
            atomicAdd(&sLoss, lse - lg[lab]);
            if (isroot && (gbase + row) == 0) {
#pragma unroll
                for (int l = 0; l < 5; l++) out[l] = lg[l] - lse;
            }
        }
    }
    __syncthreads();
    // c scatter + coalesced write
#pragma unroll
    for (int i = 0; i < 4; i++)
#pragma unroll
        for (int jj = 0; jj < 4; jj++)
#pragma unroll
            for (int r = 0; r < 4; r++) {
                const int m = wrow + i * 16 + lquad * 4 + r;
                const int j = wcol + jj * 16 + lrow;
                sT[m * 136 + j] = f2bf(cval[i][jj][r]);
            }
    __syncthreads();
#pragma unroll
    for (int s = 0; s < 8; ++s) {
        int ci = t + 256 * s;
        int row = ci >> 4, c8 = (ci & 15) * 8;
        if (row < nm)
            *(short8*)(c_all + (gbase + row) * 128 + c8) = *(const short8*)&sT[row * 136 + c8];
    }
    if (t == 0) atomicAdd(&partials[blockIdx.x & 1023], sLoss);
}

__global__ __launch_bounds__(256) void k3_reduce(const float* __restrict__ partials,
                                                 float* __restrict__ out)
{
    const int t = threadIdx.x;
    float s = 0.f;
    for (int i = t; i < 1024; i += 256) s += partials[i];
#pragma unroll
    for (int d = 32; d > 0; d >>= 1) s += __shfl_down(s, d);
    __shared__ float red[4];
    if ((t & 63) == 0) red[t >> 6] = s;
    __syncthreads();
    if (t == 0) out[5] = red[0] + red[1] + red[2] + red[3];
}

// ---------------------------------------------------------------------------
extern "C" void kernel_launch(void* const* d_in, const int* in_sizes, int n_in,
                              void* d_out, int out_size, void* d_ws, size_t ws_size,
                              hipStream_t stream)
{
    const float* embeds = (const float*)d_in[0];
    const int* words = (const int*)d_in[1];
    const int* labels = (const int*)d_in[2];
    const float* Wix = (const float*)d_in[5],  *bix  = (const float*)d_in[6];
    const float* Wih = (const float*)d_in[7],  *bih  = (const float*)d_in[8];
    const float* Wfx = (const float*)d_in[9],  *bfx  = (const float*)d_in[10];
    const float* Wfh = (const float*)d_in[11], *bfh  = (const float*)d_in[12];
    const float* Wox = (const float*)d_in[13], *box_ = (const float*)d_in[14];
    const float* Woh = (const float*)d_in[15], *boh  = (const float*)d_in[16];
    const float* Wux = (const float*)d_in[17], *bux  = (const float*)d_in[18];
    const float* Wuh = (const float*)d_in[19], *buh  = (const float*)d_in[20];
    const float* Wout = (const float*)d_in[21], *bout = (const float*)d_in[22];
    float* out = (float*)d_out;

    // Workspace: h_all, c_all (NNODES*128 bf16 = 67.1 MB each), embeds_bf
    // (12.8 MB), BcatT (0.49 MB), bias_cat, partials.  Total ~148 MB; no G.
    char* ws = (char*)d_ws;
    const size_t treeElems = (size_t)NNODES * 128;
    bf16raw* h_all = (bf16raw*)ws;
    bf16raw* c_all = h_all + treeElems;
    bf16raw* embeds_bf = c_all + treeElems;
    bf16raw* BcatT = embeds_bf + (size_t)NVOCAB * 128;
    float* bias_cat = (float*)(BcatT + 640 * 384);
    float* partials = bias_cat + 640;

    k_prep_embeds<<<(NVOCAB * 128 / 4 + 255) / 256, 256, 0, stream>>>(
        embeds, embeds_bf, NVOCAB * 128 / 4);
    k_prep_bcat<<<640, 128, 0, stream>>>(Wix, bix, Wih, bih, Wfx, bfx, Wfh, bfh,
                                         Wox, box_, Woh, boh, Wux, bux, Wuh, buh,
                                         BcatT, bias_cat);
    hipMemsetAsync(partials, 0, 1024 * sizeof(float), stream);

    for (int l = DEPTH - 1; l >= 0; --l) {
        const int n = 1 << l;
        const int off = n - 1;
        const int leaf = (l == DEPTH - 1) ? 1 : 0;
        const int nblk = (n + 127) / 128;
        k_fused<<<nblk, 256, 0, stream>>>(embeds_bf, words, h_all, c_all,
                                          BcatT, bias_cat, Wout, bout, labels,
                                          partials, out, off, n, leaf,
                                          (l == 0) ? 1 : 0);
    }
    k3_reduce<<<1, 256, 0, stream>>>(partials, out);
}

// Round 7
// 712.360 us; speedup vs baseline: 2.4765x; 2.4765x over previous
//
#include <hip/hip_runtime.h>
#include <math.h>

#define DEPTH 18
#define NNODES ((1 << DEPTH) - 1)
#define NVOCAB 50000

typedef unsigned short bf16raw;
typedef __bf16 bf16x8 __attribute__((ext_vector_type(8)));
typedef float f32x4 __attribute__((ext_vector_type(4)));
typedef short short8 __attribute__((ext_vector_type(8)));

__device__ __forceinline__ float sigm(float x) { return 1.0f / (1.0f + __expf(-x)); }

__device__ __forceinline__ float bf2f(bf16raw u) {
    union { unsigned int i; float f; } v;
    v.i = ((unsigned int)u) << 16;
    return v.f;
}
__device__ __forceinline__ bf16raw f2bf(float f) {
    union { float f; unsigned int i; } v;
    v.f = f;
    unsigned int r = v.i + 0x7FFFu + ((v.i >> 16) & 1u);  // RNE
    return (bf16raw)(r >> 16);
}

// ---------------------------------------------------------------------------
__global__ __launch_bounds__(256) void k_prep_embeds(const float* __restrict__ src,
                                                     bf16raw* __restrict__ dst, int n4)
{
    int i = blockIdx.x * blockDim.x + threadIdx.x;
    if (i < n4) {
        float4 v = ((const float4*)src)[i];
        ushort4 o;
        o.x = f2bf(v.x); o.y = f2bf(v.y); o.z = f2bf(v.z); o.w = f2bf(v.w);
        ((ushort4*)dst)[i] = o;
    }
}

// ---------------------------------------------------------------------------
// BcatT[col 0..639][k 0..383] bf16.  Gate order: 0=i, 1=u, 2=o, 3=f1, 4=f2
//  k 0-127: Wx ; k 128-255: Wh (0 for f2) ; k 256-383: Wh (0 for f1)
// ---------------------------------------------------------------------------
__global__ __launch_bounds__(128) void k_prep_bcat(
    const float* __restrict__ Wix, const float* __restrict__ bix,
    const float* __restrict__ Wih, const float* __restrict__ bih,
    const float* __restrict__ Wfx, const float* __restrict__ bfx,
    const float* __restrict__ Wfh, const float* __restrict__ bfh,
    const float* __restrict__ Wox, const float* __restrict__ box_,
    const float* __restrict__ Woh, const float* __restrict__ boh,
    const float* __restrict__ Wux, const float* __restrict__ bux,
    const float* __restrict__ Wuh, const float* __restrict__ buh,
    bf16raw* __restrict__ BcatT, float* __restrict__ bias_cat)
{
    const int j = blockIdx.x;        // 0..639
    const int grp = j >> 7, jj = j & 127;
    const float *Wx, *Wh, *bx, *bh;
    switch (grp) {
        case 0: Wx = Wix; Wh = Wih; bx = bix;  bh = bih; break;
        case 1: Wx = Wux; Wh = Wuh; bx = bux;  bh = buh; break;
        case 2: Wx = Wox; Wh = Woh; bx = box_; bh = boh; break;
        default: Wx = Wfx; Wh = Wfh; bx = bfx; bh = bfh; break;
    }
    for (int k = threadIdx.x; k < 384; k += blockDim.x) {
        float v;
        if (k < 128) {
            v = Wx[jj * 128 + k];
        } else if (k < 256) {
            v = (grp == 4) ? 0.f : Wh[jj * 128 + (k - 128)];
        } else {
            v = (grp == 3) ? 0.f : Wh[jj * 128 + (k - 256)];
        }
        BcatT[(long)j * 384 + k] = f2bf(v);
    }
    if (threadIdx.x == 0) bias_cat[j] = bx[jj] + bh[jj];
}

// ---------------------------------------------------------------------------
// k_leafpre: per-vocab leaf tables. 128 vocab rows per block (block offset
// folded in). Writes hc_leaf[v][0..127]=h, [128..255]=c and
// lossv6[v][0..4]=logits, [5]=lse.
// ---------------------------------------------------------------------------
__global__ __launch_bounds__(256, 2) void k_leafpre(
    const bf16raw* __restrict__ embeds_bf,
    const bf16raw* __restrict__ BcatT, const float* __restrict__ bias_cat,
    const float* __restrict__ Wout, const float* __restrict__ bout,
    bf16raw* __restrict__ hc_leaf, float* __restrict__ lossv6, int vbase, int nv)
{
    vbase += blockIdx.x * 128;
    nv -= vbase;
    if (nv > 128) nv = 128;
    if (nv <= 0) return;

    __shared__ __align__(16) bf16raw sA[128 * 40];
    __shared__ __align__(16) bf16raw sB[128 * 40];
    __shared__ __align__(16) bf16raw sT[128 * 136];
    __shared__ float sWout[5 * 128];

    const int t = threadIdx.x;
    for (int i = t; i < 640; i += 256) sWout[i] = Wout[i];

    const int srow = t >> 1;
    const int shalf = (t & 1) * 16;
    const int arow = (srow < nv) ? srow : 0;
    const bf16raw* ax = embeds_bf + (long)(vbase + arow) * 128;

    const int lane = t & 63;
    const int w = t >> 6;
    const int wrow = (w >> 1) * 64;
    const int wcol = (w & 1) * 64;
    const int lrow = lane & 15;
    const int lquad = lane >> 4;
    const int lkoff = lquad * 8;

    float cval[4][4][4];
    unsigned int opk[4][4][2];

    for (int cb = 0; cb < 3; ++cb) {
        const bf16raw* bsrc = BcatT + ((long)(cb * 128 + srow)) * 384;
        f32x4 acc[4][4];
#pragma unroll
        for (int i = 0; i < 4; i++)
#pragma unroll
            for (int j = 0; j < 4; j++) acc[i][j] = (f32x4){0.f, 0.f, 0.f, 0.f};

        for (int kt = 0; kt < 128; kt += 32) {
            // full 32-wide row: each of 2 threads stages 16 elems (2x short8)
            short8 av0 = *(const short8*)(ax + kt + shalf);
            short8 av1 = *(const short8*)(ax + kt + shalf + 8);
            short8 bv0 = *(const short8*)(bsrc + kt + shalf);
            short8 bv1 = *(const short8*)(bsrc + kt + shalf + 8);
            __syncthreads();
            *(short8*)&sA[srow * 40 + shalf] = av0;
            *(short8*)&sA[srow * 40 + shalf + 8] = av1;
            *(short8*)&sB[srow * 40 + shalf] = bv0;
            *(short8*)&sB[srow * 40 + shalf + 8] = bv1;
            __syncthreads();
            bf16x8 af[4], bfr[4];
#pragma unroll
            for (int i = 0; i < 4; i++) {
                af[i]  = *(const bf16x8*)&sA[(wrow + i * 16 + lrow) * 40 + lkoff];
                bfr[i] = *(const bf16x8*)&sB[(wcol + i * 16 + lrow) * 40 + lkoff];
            }
#pragma unroll
            for (int i = 0; i < 4; i++)
#pragma unroll
                for (int j = 0; j < 4; j++)
                    acc[i][j] = __builtin_amdgcn_mfma_f32_16x16x32_bf16(af[i], bfr[j], acc[i][j], 0, 0, 0);
        }
        if (cb == 0) {
#pragma unroll
            for (int i = 0; i < 4; i++)
#pragma unroll
                for (int jj = 0; jj < 4; jj++) {
                    const float bias = bias_cat[wcol + jj * 16 + lrow];
#pragma unroll
                    for (int r = 0; r < 4; r++)
                        cval[i][jj][r] = sigm(acc[i][jj][r] + bias);
                }
        } else if (cb == 1) {
#pragma unroll
            for (int i = 0; i < 4; i++)
#pragma unroll
                for (int jj = 0; jj < 4; jj++) {
                    const float bias = bias_cat[128 + wcol + jj * 16 + lrow];
#pragma unroll
                    for (int r = 0; r < 4; r++)
                        cval[i][jj][r] *= tanhf(acc[i][jj][r] + bias);
                }
        } else {
#pragma unroll
            for (int i = 0; i < 4; i++)
#pragma unroll
                for (int jj = 0; jj < 4; jj++) {
                    const float bias = bias_cat[256 + wcol + jj * 16 + lrow];
#pragma unroll
                    for (int rp = 0; rp < 2; rp++) {
                        float o0 = sigm(acc[i][jj][rp * 2] + bias);
                        float o1 = sigm(acc[i][jj][rp * 2 + 1] + bias);
                        opk[i][jj][rp] = (unsigned int)f2bf(o0) |
                                         ((unsigned int)f2bf(o1) << 16);
                    }
                }
        }
    }
    __syncthreads();
    // h into sT
#pragma unroll
    for (int i = 0; i < 4; i++)
#pragma unroll
        for (int jj = 0; jj < 4; jj++)
#pragma unroll
            for (int r = 0; r < 4; r++) {
                const int m = wrow + i * 16 + lquad * 4 + r;
                const int j = wcol + jj * 16 + lrow;
                float o = bf2f((bf16raw)((opk[i][jj][r >> 1] >> ((r & 1) * 16)) & 0xFFFF));
                sT[m * 136 + j] = f2bf(o * tanhf(cval[i][jj][r]));
            }
    __syncthreads();
#pragma unroll
    for (int s = 0; s < 8; ++s) {
        int ci = t + 256 * s;
        int row = ci >> 4, c8 = (ci & 15) * 8;
        if (row < nv)
            *(short8*)(hc_leaf + (long)(vbase + row) * 256 + c8) = *(const short8*)&sT[row * 136 + c8];
    }
    // logits (2 threads/row)
    {
        const int row = t >> 1, half = t & 1;
        float p[5] = {0.f, 0.f, 0.f, 0.f, 0.f};
        for (int k = 0; k < 64; ++k) {
            float hv = bf2f(sT[row * 136 + half * 64 + k]);
#pragma unroll
            for (int l = 0; l < 5; l++) p[l] += hv * sWout[l * 128 + half * 64 + k];
        }
#pragma unroll
        for (int l = 0; l < 5; l++) p[l] += __shfl_down(p[l], 1);
        if (half == 0 && row < nv) {
            float lg[5], mx = -1e30f;
#pragma unroll
            for (int l = 0; l < 5; l++) {
                lg[l] = p[l] + bout[l];
                mx = fmaxf(mx, lg[l]);
            }
            float se = 0.f;
#pragma unroll
            for (int l = 0; l < 5; l++) se += __expf(lg[l] - mx);
            float lse = __logf(se) + mx;
            float* dst = lossv6 + (long)(vbase + row) * 6;
#pragma unroll
            for (int l = 0; l < 5; l++) dst[l] = lg[l];
            dst[5] = lse;
        }
    }
    __syncthreads();
    // c into sT
#pragma unroll
    for (int i = 0; i < 4; i++)
#pragma unroll
        for (int jj = 0; jj < 4; jj++)
#pragma unroll
            for (int r = 0; r < 4; r++) {
                const int m = wrow + i * 16 + lquad * 4 + r;
                const int j = wcol + jj * 16 + lrow;
                sT[m * 136 + j] = f2bf(cval[i][jj][r]);
            }
    __syncthreads();
#pragma unroll
    for (int s = 0; s < 8; ++s) {
        int ci = t + 256 * s;
        int row = ci >> 4, c8 = (ci & 15) * 8;
        if (row < nv)
            *(short8*)(hc_leaf + (long)(vbase + row) * 256 + 128 + c8) = *(const short8*)&sT[row * 136 + c8];
    }
}

// ---------------------------------------------------------------------------
// k_leaf_gather: leaf level = gather h/c from vocab tables + loss lookup.
// ---------------------------------------------------------------------------
__global__ __launch_bounds__(256) void k_leaf_gather(
    const int* __restrict__ words, const int* __restrict__ labels,
    const bf16raw* __restrict__ hc_leaf, const float* __restrict__ lossv6,
    bf16raw* __restrict__ h_all, bf16raw* __restrict__ c_all,
    float* __restrict__ partials, int off, int n)
{
    __shared__ float sLoss;
    if (threadIdx.x == 0) sLoss = 0.f;
    __syncthreads();
    const int idx = blockIdx.x * 16 + (threadIdx.x >> 4);
    const int l16 = threadIdx.x & 15;
    if (idx < n) {
        const long g = (long)off + idx;
        const int wd = words[g];
        const bf16raw* src = hc_leaf + (long)wd * 256;
        *(short8*)(h_all + g * 128 + l16 * 8) = *(const short8*)(src + l16 * 8);
        *(short8*)(c_all + g * 128 + l16 * 8) = *(const short8*)(src + 128 + l16 * 8);
        if (l16 == 0) {
            const float* lv = lossv6 + (long)wd * 6;
            atomicAdd(&sLoss, lv[5] - lv[labels[g]]);
        }
    }
    __syncthreads();
    if (threadIdx.x == 0) atomicAdd(&partials[blockIdx.x & 1023], sLoss);
}

// ---------------------------------------------------------------------------
// k_gemm (internal levels): G[m][col] bf16 = [x|h1|h2].BcatT^T + bias.
// blockIdx.x = cb (gate group), blockIdx.y = m-tile.
// ---------------------------------------------------------------------------
__global__ __launch_bounds__(256) void k_gemm(
    const bf16raw* __restrict__ embeds_bf, const int* __restrict__ words,
    const bf16raw* __restrict__ h_all,
    const bf16raw* __restrict__ BcatT, const float* __restrict__ bias_cat,
    bf16raw* __restrict__ G, int off, int m0, int nm)
{
    __shared__ __align__(16) bf16raw sA[128 * 40];
    __shared__ __align__(16) bf16raw sB[128 * 40];
    __shared__ __align__(16) bf16raw sT[128 * 76];

    const int t = threadIdx.x;
    const int cb = blockIdx.x;
    const int mbase = blockIdx.y * 128;

    const int srow = t >> 1;
    const int shalf = (t & 1) * 16;
    const long glr = (long)off + m0 + mbase + srow;
    const bf16raw* ax  = embeds_bf + (long)words[glr] * 128;
    const bf16raw* ah1 = h_all + (2 * glr + 1) * 128;
    const bf16raw* ah2 = h_all + (2 * glr + 2) * 128;
    const bf16raw* bsrc = BcatT + ((long)(cb * 128 + srow)) * 384;

    const int lane = t & 63;
    const int w = t >> 6;
    const int wrow = (w >> 1) * 64;
    const int wcol = (w & 1) * 64;
    const int lrow = lane & 15;
    const int lquad = lane >> 4;
    const int lkoff = lquad * 8;

    f32x4 acc[4][4];
#pragma unroll
    for (int i = 0; i < 4; i++)
#pragma unroll
        for (int j = 0; j < 4; j++) acc[i][j] = (f32x4){0.f, 0.f, 0.f, 0.f};

    for (int kt = 0; kt < 384; kt += 32) {
        const bf16raw* asrc = (kt < 128) ? ax : ((kt < 256) ? ah1 : ah2);
        const int kl = kt & 127;
        // full 32-wide row: each of 2 threads stages 16 elems (2x short8)
        short8 av0 = *(const short8*)(asrc + kl + shalf);
        short8 av1 = *(const short8*)(asrc + kl + shalf + 8);
        short8 bv0 = *(const short8*)(bsrc + kt + shalf);
        short8 bv1 = *(const short8*)(bsrc + kt + shalf + 8);
        __syncthreads();
        *(short8*)&sA[srow * 40 + shalf] = av0;
        *(short8*)&sA[srow * 40 + shalf + 8] = av1;
        *(short8*)&sB[srow * 40 + shalf] = bv0;
        *(short8*)&sB[srow * 40 + shalf + 8] = bv1;
        __syncthreads();
        bf16x8 af[4], bfr[4];
#pragma unroll
        for (int i = 0; i < 4; i++) {
            af[i]  = *(const bf16x8*)&sA[(wrow + i * 16 + lrow) * 40 + lkoff];
            bfr[i] = *(const bf16x8*)&sB[(wcol + i * 16 + lrow) * 40 + lkoff];
        }
#pragma unroll
        for (int i = 0; i < 4; i++)
#pragma unroll
            for (int j = 0; j < 4; j++)
                acc[i][j] = __builtin_amdgcn_mfma_f32_16x16x32_bf16(af[i], bfr[j], acc[i][j], 0, 0, 0);
    }

    float bias[4];
#pragma unroll
    for (int jj = 0; jj < 4; jj++)
        bias[jj] = bias_cat[cb * 128 + wcol + jj * 16 + lrow];

    // epilogue: two 64-col half-tiles through sT (pitch 76)
#pragma unroll
    for (int half = 0; half < 2; ++half) {
        __syncthreads();
        if ((wcol >> 6) == half) {
#pragma unroll
            for (int i = 0; i < 4; i++)
#pragma unroll
                for (int jj = 0; jj < 4; jj++)
#pragma unroll
                    for (int r = 0; r < 4; r++)
                        sT[(wrow + i * 16 + lquad * 4 + r) * 76 + jj * 16 + lrow] =
                            f2bf(acc[i][jj][r] + bias[jj]);
        }
        __syncthreads();
#pragma unroll
        for (int s = 0; s < 4; ++s) {
            int ci = t + 256 * s;
            int row = ci >> 3, c8 = (ci & 7) * 8;
            int m = mbase + row;
            if (m < nm)
                *(short8*)(G + (long)m * 640 + cb * 128 + half * 64 + c8) =
                    *(const short8*)&sT[row * 76 + c8];
        }
    }
}

// ---------------------------------------------------------------------------
// k_gates (internal): gate order i,u,o,f1,f2. One 128-thread block per node.
// ---------------------------------------------------------------------------
__global__ __launch_bounds__(128) void k_gates(
    const bf16raw* __restrict__ G,
    bf16raw* __restrict__ h_all, bf16raw* __restrict__ c_all,
    const int* __restrict__ labels,
    const float* __restrict__ Wout, const float* __restrict__ bout,
    float* __restrict__ partials, float* __restrict__ out,
    int off, int m0, int isroot)
{
    const int m = blockIdx.x;
    const int j = threadIdx.x;
    const long g = (long)off + m0 + m;
    const bf16raw* Grow = G + (long)m * 640;

    float iv = sigm(bf2f(Grow[j]));
    float uv = tanhf(bf2f(Grow[128 + j]));
    float ov = sigm(bf2f(Grow[256 + j]));
    float f1 = sigm(bf2f(Grow[384 + j]));
    float f2 = sigm(bf2f(Grow[512 + j]));
    float c = iv * uv
            + f1 * bf2f(c_all[(2 * g + 1) * 128 + j])
            + f2 * bf2f(c_all[(2 * g + 2) * 128 + j]);
    float h = ov * tanhf(c);
    h_all[g * 128 + j] = f2bf(h);
    c_all[g * 128 + j] = f2bf(c);

    float p0 = h * Wout[j];
    float p1 = h * Wout[128 + j];
    float p2 = h * Wout[256 + j];
    float p3 = h * Wout[384 + j];
    float p4 = h * Wout[512 + j];
#pragma unroll
    for (int s = 32; s > 0; s >>= 1) {
        p0 += __shfl_down(p0, s);
        p1 += __shfl_down(p1, s);
        p2 += __shfl_down(p2, s);
        p3 += __shfl_down(p3, s);
        p4 += __shfl_down(p4, s);
    }
    __shared__ float red[2][5];
    if ((j & 63) == 0) {
        int wv = j >> 6;
        red[wv][0] = p0; red[wv][1] = p1; red[wv][2] = p2; red[wv][3] = p3; red[wv][4] = p4;
    }
    __syncthreads();
    if (j == 0) {
        float lg[5], mx = -1e30f;
#pragma unroll
        for (int l = 0; l < 5; l++) {
            lg[l] = red[0][l] + red[1][l] + bout[l];
            mx = fmaxf(mx, lg[l]);
        }
        float se = 0.f;
#pragma unroll
        for (int l = 0; l < 5; l++) se += __expf(lg[l] - mx);
        float lse = __logf(se) + mx;
        atomicAdd(&partials[m & 1023], lse - lg[labels[g]]);
        if (isroot) {
#pragma unroll
            for (int l = 0; l < 5; l++) out[l] = lg[l] - lse;
        }
    }
}

__global__ __launch_bounds__(256) void k3_reduce(const float* __restrict__ partials,
                                                 float* __restrict__ out)
{
    const int t = threadIdx.x;
    float s = 0.f;
    for (int i = t; i < 1024; i += 256) s += partials[i];
#pragma unroll
    for (int d = 32; d > 0; d >>= 1) s += __shfl_down(s, d);
    __shared__ float red[4];
    if ((t & 63) == 0) red[t >> 6] = s;
    __syncthreads();
    if (t == 0) out[5] = red[0] + red[1] + red[2] + red[3];
}

// ---------------------------------------------------------------------------
extern "C" void kernel_launch(void* const* d_in, const int* in_sizes, int n_in,
                              void* d_out, int out_size, void* d_ws, size_t ws_size,
                              hipStream_t stream)
{
    const float* embeds = (const float*)d_in[0];
    const int* words = (const int*)d_in[1];
    const int* labels = (const int*)d_in[2];
    const float* Wix = (const float*)d_in[5],  *bix  = (const float*)d_in[6];
    const float* Wih = (const float*)d_in[7],  *bih  = (const float*)d_in[8];
    const float* Wfx = (const float*)d_in[9],  *bfx  = (const float*)d_in[10];
    const float* Wfh = (const float*)d_in[11], *bfh  = (const float*)d_in[12];
    const float* Wox = (const float*)d_in[13], *box_ = (const float*)d_in[14];
    const float* Woh = (const float*)d_in[15], *boh  = (const float*)d_in[16];
    const float* Wux = (const float*)d_in[17], *bux  = (const float*)d_in[18];
    const float* Wuh = (const float*)d_in[19], *buh  = (const float*)d_in[20];
    const float* Wout = (const float*)d_in[21], *bout = (const float*)d_in[22];
    float* out = (float*)d_out;

    char* ws = (char*)d_ws;
    const size_t treeElems = (size_t)NNODES * 128;
    bf16raw* h_all = (bf16raw*)ws;
    bf16raw* c_all = h_all + treeElems;
    bf16raw* embeds_bf = c_all + treeElems;
    bf16raw* BcatT = embeds_bf + (size_t)NVOCAB * 128;
    bf16raw* hc_leaf = BcatT + 640 * 384;
    float* lossv6 = (float*)(hc_leaf + (size_t)NVOCAB * 256);
    float* bias_cat = lossv6 + (size_t)NVOCAB * 6;
    float* partials = bias_cat + 640;
    bf16raw* G = (bf16raw*)(partials + 1024);

    const size_t fixedBytes = (char*)G - ws;
    size_t avail = (ws_size > fixedBytes) ? (ws_size - fixedBytes) : 0;
    long cap = (long)(avail / (640 * sizeof(bf16raw)));
    int chunk = (int)((cap / 128) * 128);
    if (chunk < 128) chunk = 128;
    if (chunk > 65536) chunk = 65536;

    k_prep_embeds<<<(NVOCAB * 128 / 4 + 255) / 256, 256, 0, stream>>>(
        embeds, embeds_bf, NVOCAB * 128 / 4);
    k_prep_bcat<<<640, 128, 0, stream>>>(Wix, bix, Wih, bih, Wfx, bfx, Wfh, bfh,
                                         Wox, box_, Woh, boh, Wux, bux, Wuh, buh,
                                         BcatT, bias_cat);
    hipMemsetAsync(partials, 0, 1024 * sizeof(float), stream);

    // vocab precompute: one launch, per-block offset folded inside kernel
    k_leafpre<<<(NVOCAB + 127) / 128, 256, 0, stream>>>(
        embeds_bf, BcatT, bias_cat, Wout, bout, hc_leaf, lossv6, 0, NVOCAB);

    // leaf level: pure gather
    {
        const int n = 1 << (DEPTH - 1);
        k_leaf_gather<<<(n + 15) / 16, 256, 0, stream>>>(
            words, labels, hc_leaf, lossv6, h_all, c_all, partials, n - 1, n);
    }

    for (int l = DEPTH - 2; l >= 0; --l) {
        const int n = 1 << l;
        const int off = n - 1;
        for (int m0 = 0; m0 < n; m0 += chunk) {
            const int nm = (n - m0 < chunk) ? (n - m0) : chunk;
            dim3 g1(5, (nm + 127) / 128);
            k_gemm<<<g1, 256, 0, stream>>>(embeds_bf, words, h_all, BcatT, bias_cat,
                                           G, off, m0, nm);
            k_gates<<<nm, 128, 0, stream>>>(G, h_all, c_all, labels, Wout, bout,
                                            partials, out, off, m0, (l == 0) ? 1 : 0);
        }
    }
    k3_reduce<<<1, 256, 0, stream>>>(partials, out);
}